// Round 4
// baseline (97.564 us; speedup 1.0000x reference)
//
#include <hip/hip_runtime.h>

#define THREADS 128
#define PI_F 3.14159265358979323846f
// pad +2 float2 per 128: keeps 16B alignment for the b128 trip (P(16u) even),
// spreads the stride-64 chunk pattern of trips B/D across all even banks.
#define P(i) ((i) + (((i) >> 7) << 1))
#define ROWSZ 1038  // P(1023)=1037 -> 1038 (even: row1 base stays 16B-aligned)

__device__ __forceinline__ float2 cadd(float2 a, float2 b) { return make_float2(a.x + b.x, a.y + b.y); }
__device__ __forceinline__ float2 csub(float2 a, float2 b) { return make_float2(a.x - b.x, a.y - b.y); }
__device__ __forceinline__ float2 cmul(float2 a, float2 b) {
  return make_float2(a.x * b.x - a.y * b.y, a.x * b.y + a.y * b.x);
}
__device__ __forceinline__ float2 conjf2(float2 a) { return make_float2(a.x, -a.y); }
__device__ __forceinline__ float2 cscale(float2 a, float s) { return make_float2(a.x * s, a.y * s); }

// In-place radix-4 butterfly on (a,b,c,d) at strides q: FWD = DIF stages 2q,q;
// INV = DIT stages q,2q. w1 = exp(-/+ i*pi*j/(2q)).
template <bool INV>
__device__ __forceinline__ void bf4(float2& a, float2& b, float2& c, float2& d, float2 w1) {
  const float2 w2 = cmul(w1, w1);
  if (!INV) {
    float2 A = cadd(a, c), Cm = cmul(csub(a, c), w1);
    float2 B = cadd(b, d), Dm = cmul(csub(b, d), make_float2(w1.y, -w1.x));  // *(-i w1)
    a = cadd(A, B); b = cmul(csub(A, B), w2);
    c = cadd(Cm, Dm); d = cmul(csub(Cm, Dm), w2);
  } else {
    float2 tb = cmul(b, w2), td = cmul(d, w2);
    float2 a1 = cadd(a, tb), b1 = csub(a, tb);
    float2 cc = cadd(c, td), dd = csub(c, td);
    float2 tc = cmul(cc, w1), te = cmul(dd, make_float2(-w1.y, w1.x));  // *(i w1)
    a = cadd(a1, tc); c = csub(a1, tc);
    b = cadd(b1, te); d = csub(b1, te);
  }
}

// 128 threads = 2 waves; wave w owns row w. 2048 blocks (2 complex rows each),
// LDS ~16.6 KB -> ~9 blocks/CU (18 waves) with staggered block starts.
// 5 wave-private LDS round-trips; 2 cheap 2-wave barriers (staging / store).
__global__ __launch_bounds__(THREADS, 4) void fbp_butterfly_wv2(
    const float* __restrict__ x,
    const float* __restrict__ filt_br,
    float* __restrict__ out) {
  __shared__ __align__(16) float2 data[2][ROWSZ];

  const int t = threadIdx.x;
  const int blk = blockIdx.x;
  // Same-XCD swizzle: the 4 blocks covering one 64B x-line (8 a-pairs, same bc)
  // share blk%8 -> same XCD L2 -> line fetched once, served 4x from L2.
  const int xcd = blk & 7;
  const int rest = blk >> 3;
  const int sib = rest & 3;
  const int g = ((rest >> 2) << 3) | xcd;          // 0..511 line-group
  const int bc = g >> 5;                           // 16 (b,c) groups
  const int p0 = ((g & 31) << 3) + (sib << 1);     // a-pair base (2 pairs/block)

  const float4* __restrict__ x4 = (const float4*)x;
  float4* __restrict__ out4 = (float4*)out;

  // ---- staging in: one float4 per lane = both rows' (Re,Im) at sample s
#pragma unroll
  for (int k = 0; k < 4; ++k) {
    int s = t + (k << 7);  // 0..511
    float4 v4 = x4[(bc * 512 + s) * 128 + (p0 >> 1)];
    data[0][P(s)] = make_float2(v4.x, v4.y);
    data[1][P(s)] = make_float2(v4.z, v4.w);
  }
  __syncthreads();

  const int w = t >> 6;  // wave = row
  const int u = t & 63;
  float2* __restrict__ row = data[w];

  const float2 E8[4] = {{1.f, 0.f}, {0.92387953f, -0.38268343f},
                        {0.70710678f, -0.70710678f}, {0.38268343f, -0.92387953f}};

  // all twiddle bases up-front (forward sign); D/E use conjugates
  float2 wu, w64, wj32, wj8;
  {
    float sn, cs;
    __sincosf(-PI_F * (float)u / 512.0f, &sn, &cs); wu = make_float2(cs, sn);
    __sincosf(-PI_F * (float)u / 128.0f, &sn, &cs); w64 = make_float2(cs, sn);
    const float j3f = (float)(u & 3);
    __sincosf(-PI_F * j3f / 32.0f, &sn, &cs); wj32 = make_float2(cs, sn);
    __sincosf(-PI_F * j3f / 8.0f, &sn, &cs); wj8 = make_float2(cs, sn);
  }

  float2 v[4][4];  // element u + 64k + 256l (trips A/E) or base+4k+16l (B/D)

  // ======== Trip A: fwd q=256 (stages 512,256; upper half zero) + q=64 (128,64)
  {
#pragma unroll
    for (int k = 0; k < 4; ++k) {
      float2 a = row[P(u + 64 * k)];
      float2 b = row[P(u + 64 * k + 256)];
      const float2 w1 = cmul(wu, E8[k]);  // exp(-i pi (u+64k)/512)
      const float2 w2 = cmul(w1, w1);
      float2 Cm = cmul(a, w1);
      float2 Dm = cmul(b, make_float2(w1.y, -w1.x));
      v[k][0] = cadd(a, b);
      v[k][1] = cmul(csub(a, b), w2);
      v[k][2] = cadd(Cm, Dm);
      v[k][3] = cmul(csub(Cm, Dm), w2);
    }
#pragma unroll
    for (int l = 0; l < 4; ++l) bf4<false>(v[0][l], v[1][l], v[2][l], v[3][l], w64);
#pragma unroll
    for (int k = 0; k < 4; ++k)
#pragma unroll
      for (int l = 0; l < 4; ++l) row[P(u + 64 * k + 256 * l)] = v[k][l];
  }

  // ======== Trip B: fwd q=16 (32,16) + q=4 (8,4)
  {
    const int base = ((u >> 2) << 6) + (u & 3);
#pragma unroll
    for (int k = 0; k < 4; ++k)
#pragma unroll
      for (int l = 0; l < 4; ++l) v[k][l] = row[P(base + 4 * k + 16 * l)];
#pragma unroll
    for (int k = 0; k < 4; ++k) bf4<false>(v[k][0], v[k][1], v[k][2], v[k][3], cmul(wj32, E8[k]));
#pragma unroll
    for (int l = 0; l < 4; ++l) bf4<false>(v[0][l], v[1][l], v[2][l], v[3][l], wj8);
#pragma unroll
    for (int k = 0; k < 4; ++k)
#pragma unroll
      for (int l = 0; l < 4; ++l) row[P(base + 4 * k + 16 * l)] = v[k][l];
  }

  // ======== Trip C: 16 consecutive: fwd h=2,1 + BR filter (*1/1024) + inv h=1,2
  {
    float4* rp = (float4*)&row[P(u << 4)];  // contiguous & 16B-aligned
    const float4* f4p = (const float4*)filt_br;
    const float sc = 1.0f / 1024.0f;
#pragma unroll
    for (int c = 0; c < 4; ++c) {
      float4 lo = rp[2 * c], hi = rp[2 * c + 1];
      float2 a = make_float2(lo.x, lo.y), b = make_float2(lo.z, lo.w);
      float2 cq = make_float2(hi.x, hi.y), d = make_float2(hi.z, hi.w);
      float2 A = cadd(a, cq), Cm = csub(a, cq);
      float2 B = cadd(b, d);
      float2 Dm = make_float2(b.y - d.y, d.x - b.x);  // (b-d)*(-i)
      float2 o0 = cadd(A, B), o1 = csub(A, B), o2 = cadd(Cm, Dm), o3 = csub(Cm, Dm);
      const float4 f = f4p[(u << 2) + c];
      o0 = cscale(o0, f.x * sc); o1 = cscale(o1, f.y * sc);
      o2 = cscale(o2, f.z * sc); o3 = cscale(o3, f.w * sc);
      float2 a1 = cadd(o0, o1), b1 = csub(o0, o1);
      float2 cc = cadd(o2, o3), dd = csub(o2, o3);
      float2 te = make_float2(-dd.y, dd.x);  // i*dd
      rp[2 * c]     = make_float4(a1.x + cc.x, a1.y + cc.y, b1.x + te.x, b1.y + te.y);
      rp[2 * c + 1] = make_float4(a1.x - cc.x, a1.y - cc.y, b1.x - te.x, b1.y - te.y);
    }
  }

  // ======== Trip D: inv q=4 (4,8) + q=16 (16,32)  [conjugate twiddles of B]
  {
    const int base = ((u >> 2) << 6) + (u & 3);
#pragma unroll
    for (int k = 0; k < 4; ++k)
#pragma unroll
      for (int l = 0; l < 4; ++l) v[k][l] = row[P(base + 4 * k + 16 * l)];
#pragma unroll
    for (int l = 0; l < 4; ++l) bf4<true>(v[0][l], v[1][l], v[2][l], v[3][l], conjf2(wj8));
#pragma unroll
    for (int k = 0; k < 4; ++k) bf4<true>(v[k][0], v[k][1], v[k][2], v[k][3], conjf2(cmul(wj32, E8[k])));
#pragma unroll
    for (int k = 0; k < 4; ++k)
#pragma unroll
      for (int l = 0; l < 4; ++l) row[P(base + 4 * k + 16 * l)] = v[k][l];
  }

  // ======== Trip E: inv q=64 (64,128) + q=256 (256,512; only s<512 emitted)
  {
#pragma unroll
    for (int k = 0; k < 4; ++k)
#pragma unroll
      for (int l = 0; l < 4; ++l) v[k][l] = row[P(u + 64 * k + 256 * l)];
#pragma unroll
    for (int l = 0; l < 4; ++l) bf4<true>(v[0][l], v[1][l], v[2][l], v[3][l], conjf2(w64));
#pragma unroll
    for (int k = 0; k < 4; ++k) {
      const float2 w1 = conjf2(cmul(wu, E8[k]));  // exp(+i pi (u+64k)/512)
      const float2 w2 = cmul(w1, w1);
      float2 tb = cmul(v[k][1], w2), td = cmul(v[k][3], w2);
      float2 a1 = cadd(v[k][0], tb), b1 = csub(v[k][0], tb);
      float2 cc = cadd(v[k][2], td), dd = csub(v[k][2], td);
      row[P(u + 64 * k)]       = cadd(a1, cmul(cc, w1));                        // s = u+64k
      row[P(u + 64 * k + 256)] = cadd(b1, cmul(dd, make_float2(-w1.y, w1.x)));  // s+256
    }
  }
  __syncthreads();

  // ---- store: scrambled proj.T.reshape layout (validated R1-R3); both rows of
  // the block are adjacent float2s -> one float4 per lane.
#pragma unroll
  for (int k = 0; k < 4; ++k) {
    int s = t + (k << 7);  // 0..511
    float2 r0 = data[0][P(s)];
    float2 r1 = data[1][P(s)];
    int o4 = 65536 * (s >> 5) + 128 * (16 * (s & 31) + bc) + (p0 >> 1);
    out4[o4] = make_float4(r0.x, r0.y, r1.x, r1.y);
  }
}

extern "C" void kernel_launch(void* const* d_in, const int* in_sizes, int n_in,
                              void* d_out, int out_size, void* d_ws, size_t ws_size,
                              hipStream_t stream) {
  const float* x = (const float*)d_in[0];
  // d_in[1] = twiddle_fft, d_in[2] = twiddle_ifft (recomputed on the fly)
  const float* filt = (const float*)d_in[3];
  float* out = (float*)d_out;
  (void)in_sizes; (void)n_in; (void)out_size; (void)d_ws; (void)ws_size;

  hipLaunchKernelGGL(fbp_butterfly_wv2, dim3(2048), dim3(THREADS), 0, stream,
                     x, filt, out);
}

// Round 5
// 92.429 us; speedup vs baseline: 1.0556x; 1.0556x over previous
//
#include <hip/hip_runtime.h>

typedef _Float16 half8 __attribute__((ext_vector_type(8)));
typedef float floatx4 __attribute__((ext_vector_type(4)));

#define TWO_PI_OVER_1024 0.006135923151542565f

// ===================== Kernel A: c[d] = (1/1024) sum_k H_k cos(2*pi*k*d/1024)
// filt_br holds H in bit-reversed order: k = bitrev10(i).
// 16 blocks x 256 threads: block owns 64 d's, 4 partial sums per d.
__global__ __launch_bounds__(256) void build_c_kernel(
    const float* __restrict__ filt_br, float* __restrict__ c_ws) {
  __shared__ float part[4][64];
  const int t = threadIdx.x;
  const int dd = t & 63, q = t >> 6;
  const int d = (blockIdx.x << 6) + dd;
  float sum = 0.f;
  for (int i = q * 256; i < q * 256 + 256; ++i) {
    int k = __brev((unsigned)i) >> 22;        // bitrev10
    int m = (k * d) & 1023;
    sum += filt_br[i] * __cosf((float)m * TWO_PI_OVER_1024);
  }
  part[q][dd] = sum;
  __syncthreads();
  if (t < 64) {
    float s = part[0][t] + part[1][t] + part[2][t] + part[3][t];
    c_ws[(blockIdx.x << 6) + t] = s * (1.0f / 1024.0f);
  }
}

// ===================== Kernel BC (fused): blocks 0..127 build K f16 (512x512,
// K[i][j] = c[(i-j)&1023], symmetric); blocks 128..1151 transpose+convert x
// (16 bc x 64 tiles of 64x64): xT[bc][a][s] f16.
__global__ __launch_bounds__(256) void build_K_xT_kernel(
    const float* __restrict__ x, const float* __restrict__ c_ws,
    _Float16* __restrict__ K_ws, _Float16* __restrict__ xT_ws) {
  const int t = threadIdx.x;
  if (blockIdx.x < 128) {
    // ---- K build: block covers rows blk*4 .. +3 (4 rows x 512)
    const int base = (blockIdx.x << 11) + (t << 3);  // element index, 8 per thread
    const int i = base >> 9;
    const int j0 = base & 511;
    _Float16 vals[8];
#pragma unroll
    for (int jj = 0; jj < 8; ++jj) vals[jj] = (_Float16)c_ws[(i - (j0 + jj)) & 1023];
    *(uint4*)(K_ws + base) = *(const uint4*)vals;
  } else {
    // ---- x transpose tile: 64x64
    __shared__ float tile[64][65];
    const int id = blockIdx.x - 128;
    const int bc = id >> 6;
    const int tl = id & 63;
    const int s0 = (tl & 7) << 6;   // s-tile
    const int a0 = (tl >> 3) << 6;  // a-tile
    const float4* __restrict__ x4 = (const float4*)x;
#pragma unroll
    for (int p = 0; p < 4; ++p) {
      int r = (p << 4) + (t >> 4);   // 0..63 (s within tile)
      int c4 = t & 15;               // float4 col
      float4 v = x4[(bc * 262144 + (s0 + r) * 512 + a0 + (c4 << 2)) >> 2];
      tile[r][(c4 << 2) + 0] = v.x;
      tile[r][(c4 << 2) + 1] = v.y;
      tile[r][(c4 << 2) + 2] = v.z;
      tile[r][(c4 << 2) + 3] = v.w;
    }
    __syncthreads();
#pragma unroll
    for (int p = 0; p < 2; ++p) {
      int ar = (p << 5) + (t >> 3);  // a within tile, 0..63
      int ch = t & 7;                // s-chunk of 8
      _Float16 vals[8];
#pragma unroll
      for (int jj = 0; jj < 8; ++jj) vals[jj] = (_Float16)tile[(ch << 3) + jj][ar];
      *(uint4*)(xT_ws + bc * 262144 + (a0 + ar) * 512 + s0 + (ch << 3)) =
          *(const uint4*)vals;
    }
  }
}

// ===================== Kernel D: batched GEMM out[bc] = K * x[bc]
// M=N=K=512 per bc; BM=BN=BK=64; 256 threads (4 waves, 2x2 of 32x32);
// mfma_f32_16x16x32_f16; LDS row stride 72 f16 (144 B: 16B-aligned, conflict-floor).
#define LSTR 72
__global__ __launch_bounds__(256, 4) void gemm_filter_kernel(
    const _Float16* __restrict__ K_ws, const _Float16* __restrict__ xT_ws,
    float* __restrict__ out) {
  __shared__ __align__(16) _Float16 lA[64 * LSTR];
  __shared__ __align__(16) _Float16 lB[64 * LSTR];

  const int t = threadIdx.x;
  const int bid = blockIdx.x;
  const int bc = bid >> 6;
  const int mt = (bid >> 3) & 7, nt = bid & 7;
  const int m0 = mt << 6, n0 = nt << 6;

  const int w = t >> 6, lane = t & 63;
  const int m_w = (w >> 1) << 5, n_w = (w & 1) << 5;
  const int fl = lane & 15, q = lane >> 4;

  const _Float16* __restrict__ Bsrc = xT_ws + bc * 262144;

  floatx4 acc[2][2] = {};

  // staging assignment: thread covers chunks t and t+256 (chunk = row*8 + cc)
  const int r0 = t >> 3, cc0 = t & 7;       // chunk t
  const int r1 = 32 + (t >> 3);             // chunk t+256

  for (int kt = 0; kt < 8; ++kt) {
    const int k0 = kt << 6;
    __syncthreads();
    // ---- stage A (K matrix) and B (xT) tiles: 64x64 f16 each
    *(uint4*)(lA + r0 * LSTR + (cc0 << 3)) =
        *(const uint4*)(K_ws + (m0 + r0) * 512 + k0 + (cc0 << 3));
    *(uint4*)(lA + r1 * LSTR + (cc0 << 3)) =
        *(const uint4*)(K_ws + (m0 + r1) * 512 + k0 + (cc0 << 3));
    *(uint4*)(lB + r0 * LSTR + (cc0 << 3)) =
        *(const uint4*)(Bsrc + (n0 + r0) * 512 + k0 + (cc0 << 3));
    *(uint4*)(lB + r1 * LSTR + (cc0 << 3)) =
        *(const uint4*)(Bsrc + (n0 + r1) * 512 + k0 + (cc0 << 3));
    __syncthreads();
    // ---- compute: 2 k-steps of 32, 2x2 frags
#pragma unroll
    for (int ks = 0; ks < 2; ++ks) {
      half8 af[2], bf[2];
#pragma unroll
      for (int mb = 0; mb < 2; ++mb)
        af[mb] = *(const half8*)(lA + (m_w + (mb << 4) + fl) * LSTR + (ks << 5) + (q << 3));
#pragma unroll
      for (int nb = 0; nb < 2; ++nb)
        bf[nb] = *(const half8*)(lB + (n_w + (nb << 4) + fl) * LSTR + (ks << 5) + (q << 3));
#pragma unroll
      for (int mb = 0; mb < 2; ++mb)
#pragma unroll
        for (int nb = 0; nb < 2; ++nb)
          acc[mb][nb] = __builtin_amdgcn_mfma_f32_16x16x32_f16(af[mb], bf[nb], acc[mb][nb], 0, 0, 0);
    }
  }

  // ---- store: scrambled proj.T.reshape layout (validated R1-R4):
  // float idx = 262144*(s'>>5) + 512*(16*(s'&31)+bc) + a
#pragma unroll
  for (int mb = 0; mb < 2; ++mb) {
#pragma unroll
    for (int reg = 0; reg < 4; ++reg) {
      int sp = m0 + m_w + (mb << 4) + (q << 2) + reg;
      int rowbase = 262144 * (sp >> 5) + 512 * (16 * (sp & 31) + bc);
#pragma unroll
      for (int nb = 0; nb < 2; ++nb) {
        int a = n0 + n_w + (nb << 4) + fl;
        out[rowbase + a] = acc[mb][nb][reg];
      }
    }
  }
}

extern "C" void kernel_launch(void* const* d_in, const int* in_sizes, int n_in,
                              void* d_out, int out_size, void* d_ws, size_t ws_size,
                              hipStream_t stream) {
  const float* x = (const float*)d_in[0];
  // d_in[1] = twiddle_fft, d_in[2] = twiddle_ifft (folded into c analytically)
  const float* filt = (const float*)d_in[3];
  float* out = (float*)d_out;
  (void)in_sizes; (void)n_in; (void)out_size; (void)ws_size;

  // ws layout: c fp32 [1024] @ 0; K f16 [512*512] @ 4096 B; xT f16 [16*512*512] @ 4096+524288
  float* c_ws = (float*)d_ws;
  _Float16* K_ws = (_Float16*)((char*)d_ws + 4096);
  _Float16* xT_ws = (_Float16*)((char*)d_ws + 4096 + 524288);

  hipLaunchKernelGGL(build_c_kernel, dim3(16), dim3(256), 0, stream, filt, c_ws);
  hipLaunchKernelGGL(build_K_xT_kernel, dim3(1152), dim3(256), 0, stream,
                     x, c_ws, K_ws, xT_ws);
  hipLaunchKernelGGL(gemm_filter_kernel, dim3(1024), dim3(256), 0, stream,
                     K_ws, xT_ws, out);
}